// Round 9
// baseline (191.357 us; speedup 1.0000x reference)
//
#include <hip/hip_runtime.h>

// Rotation of (32,3,512,512) fp32 by 15 degrees, bilinear, border=0.
// Persistent-block, double-buffered pipeline: 1024 blocks x 12 tiles each.
// Per tile (64x32 output): stage next tile's rotated footprint (50x76 fp32,
// 16B-aligned origin) via global_load_lds width=16 into the alternate LDS
// buffer, compute current tile's bilinear taps from LDS, one barrier per tile
// (its vmcnt drain hides under compute), stores issued after the barrier.
// Out-of-image footprint cells are address-clamped finite garbage, masked
// exactly to zero by validity weights: matches reference  vals * (w*valid).

#define IMG_H 512
#define IMG_W 512
#define NPLANES 96
#define TSX 64
#define TSY 32
#define LROWS 50
#define LCOLS 76              // footprint col stride (73 needed, pad to 76)
#define GPR 19                // 16B groups per footprint row
#define BUF_FLOATS 4096       // 4*256 groups * 4 floats = 16 KB per buffer
#define NBLOCKS 1024
#define TPB 12                // tiles per block (96*128 / 1024)

typedef __attribute__((address_space(1))) const float gfloat;
typedef __attribute__((address_space(3))) float sfloat;

struct TileGeom {
    int X0, Y0, xs0a, ys0, bc;
    bool interior;
};

__device__ __forceinline__ TileGeom decode(int tl, float a, float b) {
    TileGeom g;
    g.bc = tl >> 7;                 // 128 tiles per plane
    const int rem = tl & 127;
    g.X0 = (rem & 7) * TSX;         // 8 tiles across
    g.Y0 = (rem >> 3) * TSY;        // 16 tiles down
    // Footprint origin — identical fp op shapes to per-pixel math, so
    // monotone fp rounding keeps every tap inside [0,LROWS)x[0,LCOLS).
    const float fx_lo = (float)g.X0 - 256.0f;
    const float fy_lo = (float)g.Y0 - 256.0f;
    const float fy_hi = (float)(g.Y0 + TSY - 1) - 256.0f;
    const float xs_min = a * fx_lo + (-b * fy_hi + 256.0f);
    const float ys_min = b * fx_lo + ( a * fy_lo + 256.0f);
    const int xs0 = (int)floorf(xs_min);
    g.ys0 = (int)floorf(ys_min);
    g.xs0a = xs0 & ~3;              // 16B-aligned column origin
    g.interior = (g.xs0a >= 0) && (g.xs0a + LCOLS <= IMG_W) &&
                 (g.ys0 >= 0) && (g.ys0 + LROWS <= IMG_H);
    return g;
}

template <bool MASKED>
__device__ __forceinline__ void compute_px(const float* __restrict__ buf,
                                           const TileGeom& G, int t,
                                           float a, float b, float4 res[2]) {
    const int col4 = (t & 15) << 2;
    const int row_base = t >> 4;
#pragma unroll
    for (int rr = 0; rr < 2; ++rr) {
        const int y = G.Y0 + row_base + (rr << 4);
        const float fy = (float)y - 256.0f;
        const float bxs = -b * fy + 256.0f;
        const float bys =  a * fy + 256.0f;

        float o[4];
#pragma unroll
        for (int k = 0; k < 4; ++k) {
            const int x = G.X0 + col4 + k;
            const float fx = (float)x - 256.0f;
            const float xs = a * fx + bxs;
            const float ys = b * fx + bys;

            const float x0f = floorf(xs);
            const float y0f = floorf(ys);
            const float wx = xs - x0f;
            const float wy = ys - y0f;
            const int x0 = (int)x0f;
            const int y0 = (int)y0f;

            float w00 = (1.0f - wy) * (1.0f - wx);
            float w01 = (1.0f - wy) * wx;
            float w10 = wy * (1.0f - wx);
            float w11 = wy * wx;

            if (MASKED) {
                const float vx0 = ((unsigned)x0       < IMG_W) ? 1.0f : 0.0f;
                const float vx1 = ((unsigned)(x0 + 1) < IMG_W) ? 1.0f : 0.0f;
                const float vy0 = ((unsigned)y0       < IMG_H) ? 1.0f : 0.0f;
                const float vy1 = ((unsigned)(y0 + 1) < IMG_H) ? 1.0f : 0.0f;
                w00 *= vy0 * vx0;
                w01 *= vy0 * vx1;
                w10 *= vy1 * vx0;
                w11 *= vy1 * vx1;
            }

            const int lr = y0 - G.ys0;
            const int lc = x0 - G.xs0a;
            const float* __restrict__ p = &buf[lr * LCOLS + lc];
            const float v00 = p[0];
            const float v01 = p[1];
            const float v10 = p[LCOLS];
            const float v11 = p[LCOLS + 1];

            o[k] = v00 * w00 + v01 * w01 + v10 * w10 + v11 * w11;
        }
        res[rr] = make_float4(o[0], o[1], o[2], o[3]);
    }
}

__device__ __forceinline__ void store_px(float* __restrict__ out,
                                         const TileGeom& G, int t,
                                         const float4 res[2]) {
    const int col4 = (t & 15) << 2;
    const int row_base = t >> 4;
    float* __restrict__ dst = out + (size_t)G.bc * (IMG_H * IMG_W);
#pragma unroll
    for (int rr = 0; rr < 2; ++rr) {
        const int y = G.Y0 + row_base + (rr << 4);
        *reinterpret_cast<float4*>(&dst[y * IMG_W + G.X0 + col4]) = res[rr];
    }
}

__global__ __launch_bounds__(256, 4) void rot_kernel(const float* __restrict__ in,
                                                     float* __restrict__ out) {
    const float a = 0.96592582628906831f;  // cos(15 deg)
    const float b = 0.25881904510252074f;  // sin(15 deg)

    __shared__ float tile[2][BUF_FLOATS];

    const int t = threadIdx.x;
    const int wave = t >> 6;
    const int total = NPLANES * IMG_H * IMG_W;

    // Per-thread staging geometry, invariant across tiles.
    int gof[4], ldso[4];
#pragma unroll
    for (int it = 0; it < 4; ++it) {
        const int g = it * 256 + t;          // 16B-group id, 0..1023
        const int r = g / GPR;               // footprint row (pad rows clamp)
        const int c4 = (g - r * GPR) << 2;
        gof[it] = r * IMG_W + c4;
        ldso[it] = (it * 256 + (wave << 6)) * 4;
    }

    auto stage = [&](const TileGeom& G, int p) {
        const int base = G.bc * (IMG_H * IMG_W) + G.ys0 * IMG_W + G.xs0a;
#pragma unroll
        for (int it = 0; it < 4; ++it) {
            int gidx = base + gof[it];
            gidx = min(max(gidx, 0), total - 4);
            __builtin_amdgcn_global_load_lds(
                (gfloat*)(in + gidx), (sfloat*)&tile[p][ldso[it]], 16, 0, 0);
        }
    };

    const int tile0 = blockIdx.x * TPB;

    TileGeom G = decode(tile0, a, b);
    stage(G, 0);
    __syncthreads();                         // drain prologue stage

    float4 res[2];
#pragma unroll 2
    for (int i = 0; i < TPB; ++i) {
        const int p = i & 1;
        TileGeom Gn;
        if (i + 1 < TPB) {                   // block-uniform branch
            Gn = decode(tile0 + i + 1, a, b);
            stage(Gn, p ^ 1);                // loads fly under compute
        }
        if (G.interior)
            compute_px<false>(&tile[p][0], G, t, a, b, res);
        else
            compute_px<true>(&tile[p][0], G, t, a, b, res);
        __syncthreads();                     // drains stage(i+1); ds_reads done
        store_px(out, G, t, res);            // stores drain at NEXT barrier
        G = Gn;
    }
}

extern "C" void kernel_launch(void* const* d_in, const int* in_sizes, int n_in,
                              void* d_out, int out_size, void* d_ws, size_t ws_size,
                              hipStream_t stream) {
    const float* in = (const float*)d_in[0];
    float* out = (float*)d_out;
    rot_kernel<<<NBLOCKS, 256, 0, stream>>>(in, out);
}